// Round 7
// baseline (792.067 us; speedup 1.0000x reference)
//
#include <hip/hip_runtime.h>

// GCN layer: out = A_sparse @ (X @ W) + bias
// R7: (a) gemm and pass1 are independent -> fused one-kernel block
// specialization (concurrent); (b) pass2 sort deleted: buckets are 128 rows
// (row>>7, 392 buckets) and gather accumulates unsorted bucket edges into a
// 64KB LDS f32 tile with ds_add_f32, then writes out+bias coalesced.

#define N_NODES 50000
#define N_EDGES 800000
#define D 128
#define NBUCKET 392            // bucket = row >> 7; 392*128 = 50176 covers rows
#define SLOT 2560              // per-bucket capacity (mean 2041, +11.5 sigma)
#define CHUNK 2048             // edges per pass1 block
#define EPT 8                  // CHUNK/256
#define GEMM_BLOCKS 782        // ceil(50000/64)
#define PASS1_BLOCKS 391       // ceil(800000/2048)

typedef short bf16x8 __attribute__((ext_vector_type(8)));
typedef float f32x4 __attribute__((ext_vector_type(4)));

__device__ inline unsigned short f2bf(float f) {   // RNE f32 -> bf16 bits
    unsigned u = __float_as_uint(f);
    unsigned r = (u + 0x7FFFu + ((u >> 16) & 1u)) >> 16;
    return (unsigned short)r;
}

// ---- ws layout (bytes) ----
// S16:      [0, 12800000)            50000*128*2 bf16
// staging:  [12800000, 20828160)     392*2560 int2 (row<<16|col, bits(w))
// gcursor:  [20828160, +1568)        392 bucket cursors

// ---------------- K0: zero bucket cursors ----------------
__global__ void zero_kernel(int* __restrict__ gcursor) {
    int t = threadIdx.x;
    if (t < NBUCKET) gcursor[t] = 0;
}

// ---------------- K1: fused gemm (blocks < GEMM_BLOCKS) + pass1 ------------
__global__ __launch_bounds__(256) void fused_kernel(const float* __restrict__ X,
                                                    const float* __restrict__ W,
                                                    unsigned short* __restrict__ S16,
                                                    const int* __restrict__ ei,
                                                    const float* __restrict__ ew,
                                                    int* __restrict__ gcursor,
                                                    int2* __restrict__ staging) {
    __shared__ __align__(16) char shmem[52224];
    const int t = threadIdx.x;
    const int lane = t & 63, wid = t >> 6;

    if (blockIdx.x < GEMM_BLOCKS) {
        // ================= GEMM: S16 = bf16(X @ W) =================
        unsigned short* wt = (unsigned short*)shmem;            // [128][136]
        unsigned short* xt = (unsigned short*)(shmem + 34816);  // [64][136]
        const int row0 = blockIdx.x * 64;

#pragma unroll
        for (int i = 0; i < 64; ++i) {
            int idx = t + 256 * i;            // flat over [k][n]
            float w = W[idx];
            int k = idx >> 7, n = idx & 127;
            wt[n * 136 + k] = f2bf(w);
        }
        const float4* X4 = (const float4*)X;
#pragma unroll
        for (int i = 0; i < 8; ++i) {
            int idx4 = t + 256 * i;
            int r = idx4 >> 5, c4 = idx4 & 31;
            int gr = row0 + r;
            float4 v = make_float4(0.f, 0.f, 0.f, 0.f);
            if (gr < N_NODES) v = X4[gr * 32 + c4];
            ushort4 u = make_ushort4(f2bf(v.x), f2bf(v.y), f2bf(v.z), f2bf(v.w));
            *(ushort4*)&xt[r * 136 + c4 * 4] = u;
        }
        __syncthreads();

        const int m = lane & 15;
        const int q = lane >> 4;
        const int rbase = wid * 16;

        f32x4 acc[8];
#pragma unroll
        for (int nt = 0; nt < 8; ++nt) acc[nt] = (f32x4){0.f, 0.f, 0.f, 0.f};
#pragma unroll
        for (int ks = 0; ks < 4; ++ks) {
            bf16x8 a = *(const bf16x8*)&xt[(rbase + m) * 136 + ks * 32 + q * 8];
#pragma unroll
            for (int nt = 0; nt < 8; ++nt) {
                bf16x8 b = *(const bf16x8*)&wt[(nt * 16 + m) * 136 + ks * 32 + q * 8];
                acc[nt] = __builtin_amdgcn_mfma_f32_16x16x32_bf16(a, b, acc[nt], 0, 0, 0);
            }
        }
        __syncthreads();
#pragma unroll
        for (int nt = 0; nt < 8; ++nt) {
            int col = nt * 16 + m;
#pragma unroll
            for (int r = 0; r < 4; ++r) {
                int rl = rbase + q * 4 + r;
                xt[rl * 136 + col] = f2bf(acc[nt][r]);
            }
        }
        __syncthreads();
#pragma unroll
        for (int i = 0; i < 4; ++i) {
            int id = t + 256 * i;
            int r = id >> 4, c8 = (id & 15) * 8;
            int gr = row0 + r;
            if (gr < N_NODES)
                *(uint4*)&S16[gr * 128 + c8] = *(const uint4*)&xt[r * 136 + c8];
        }
    } else {
        // ================= PASS1: bucket multisplit (392 buckets) =========
        int2* buf            = (int2*)shmem;                        // [2048]
        unsigned short* bof  = (unsigned short*)(shmem + 16384);    // [2048]
        int* hist            = (int*)(shmem + 20480);               // [512]
        int* lcur            = (int*)(shmem + 22528);               // [512]
        int* bmg             = (int*)(shmem + 24576);               // [512]
        int* wsum            = (int*)(shmem + 26624);               // [4]
        const int base = (blockIdx.x - GEMM_BLOCKS) * CHUNK;

        hist[t] = 0;
        hist[t + 256] = 0;
        __syncthreads();

        int rows[EPT];
#pragma unroll
        for (int i = 0; i < EPT; ++i) {
            int e = base + t + 256 * i;
            rows[i] = (e < N_EDGES) ? ei[e] : -1;
            if (rows[i] >= 0) atomicAdd(&hist[rows[i] >> 7], 1);
        }
        __syncthreads();

        // two-phase wave-shfl exclusive scan of hist[512]
        int run = 0, exv[2], vv[2];
#pragma unroll
        for (int ph = 0; ph < 2; ++ph) {
            int v = hist[ph * 256 + t];
            vv[ph] = v;
            int incl = v;
#pragma unroll
            for (int off = 1; off < 64; off <<= 1) {
                int x = __shfl_up(incl, off, 64);
                if (lane >= off) incl += x;
            }
            if (lane == 63) wsum[wid] = incl;
            __syncthreads();
            int pre = 0, tot = 0;
#pragma unroll
            for (int w = 0; w < 4; ++w) {
                int x = wsum[w];
                if (w < wid) pre += x;
                tot += x;
            }
            exv[ph] = run + incl - v + pre;
            run += tot;
            __syncthreads();
        }
        const int total = run;
        lcur[t] = exv[0];
        lcur[t + 256] = exv[1];
#pragma unroll
        for (int ph = 0; ph < 2; ++ph) {
            int b = ph * 256 + t;
            if (b < NBUCKET) {
                int v = vv[ph];
                int gb = 0;
                if (v > 0) gb = atomicAdd(&gcursor[b], v);
                bmg[b] = b * SLOT + gb - exv[ph];
            }
        }
        __syncthreads();

        // local reorder into bucket-contiguous LDS
#pragma unroll
        for (int i = 0; i < EPT; ++i) {
            if (rows[i] >= 0) {
                int e = base + t + 256 * i;
                int col = ei[N_EDGES + e];
                float w = ew[e];
                int b = rows[i] >> 7;
                int lp = atomicAdd(&lcur[b], 1);
                buf[lp] = make_int2((int)(((unsigned)rows[i] << 16) | (unsigned)col),
                                    __float_as_int(w));
                bof[lp] = (unsigned short)b;
            }
        }
        __syncthreads();

        // coalesced sweep: consecutive lp in same bucket -> consecutive gaddr
        for (int lp = t; lp < total; lp += 256) {
            int b = bof[lp];
            int g = bmg[b] + lp;
            if (g < (b + 1) * SLOT) staging[g] = buf[lp];   // overflow guard
        }
    }
}

// ---------------- K2: per-bucket LDS-accumulated gather ----------------
// One block per 128-row bucket; 1024 threads; 64KB f32 LDS tile.
// Half-wave (32 lanes) per edge: broadcast staging read, 2 coalesced dword
// S16 loads (4 bf16 each), 4 ds_add_f32 into accum[r][*]. Epilogue: +bias,
// coalesced float4 store.
__global__ __launch_bounds__(1024) void gather_kernel(const unsigned short* __restrict__ S16,
                                                      const int* __restrict__ gcursor,
                                                      const int2* __restrict__ staging,
                                                      const float* __restrict__ bias,
                                                      float* __restrict__ out) {
    __shared__ float accum[128 * 128];   // 64 KB
    const int t = threadIdx.x;
    const int b = blockIdx.x;

    float4 z = make_float4(0.f, 0.f, 0.f, 0.f);
#pragma unroll
    for (int i = 0; i < 4; ++i) ((float4*)accum)[t + 1024 * i] = z;

    int cnt = gcursor[b];
    if (cnt > SLOT) cnt = SLOT;
    __syncthreads();

    const int grp = t >> 5;            // 0..31 edge sub-streams
    const int q = t & 31;
    const unsigned* S32 = (const unsigned*)S16;   // 2 bf16 per uint, row = 64 uints
    for (int i = grp; i < cnt; i += 32) {
        int2 cw = staging[b * SLOT + i];
        float w = __int_as_float(cw.y);
        int col = cw.x & 0xFFFF;
        int r = (int)(((unsigned)cw.x >> 16) & 127u);
        unsigned u0 = S32[col * 64 + q];          // dims 2q, 2q+1
        unsigned u1 = S32[col * 64 + 32 + q];     // dims 64+2q, 65+2q
        float* arow = &accum[r * 128];
        atomicAdd(&arow[q * 2],      __uint_as_float(u0 << 16) * w);
        atomicAdd(&arow[q * 2 + 1],  __uint_as_float(u0 & 0xFFFF0000u) * w);
        atomicAdd(&arow[64 + q * 2], __uint_as_float(u1 << 16) * w);
        atomicAdd(&arow[65 + q * 2], __uint_as_float(u1 & 0xFFFF0000u) * w);
    }
    __syncthreads();

    const float4* bias4 = (const float4*)bias;
#pragma unroll
    for (int i = 0; i < 4; ++i) {
        int idx = t + 1024 * i;            // over 4096 float4 of the tile
        int r = idx >> 5, c4 = idx & 31;
        int gr = b * 128 + r;
        if (gr < N_NODES) {
            float4 a = ((const float4*)accum)[idx];
            float4 bb = bias4[c4];
            ((float4*)out)[gr * 32 + c4] =
                make_float4(a.x + bb.x, a.y + bb.y, a.z + bb.z, a.w + bb.w);
        }
    }
}

extern "C" void kernel_launch(void* const* d_in, const int* in_sizes, int n_in,
                              void* d_out, int out_size, void* d_ws, size_t ws_size,
                              hipStream_t stream) {
    const float* X    = (const float*)d_in[0];
    const int*   ei   = (const int*)d_in[1];
    const float* ew   = (const float*)d_in[2];
    const float* W    = (const float*)d_in[3];
    const float* bias = (const float*)d_in[4];
    float* out = (float*)d_out;

    char* ws = (char*)d_ws;
    unsigned short* S16 = (unsigned short*)(ws);
    int2* staging = (int2*)(ws + 12800000);
    int*  gcursor = (int*)(ws + 20828160);

    zero_kernel<<<1, 512, 0, stream>>>(gcursor);
    fused_kernel<<<GEMM_BLOCKS + PASS1_BLOCKS, 256, 0, stream>>>(X, W, S16, ei, ew,
                                                                 gcursor, staging);
    gather_kernel<<<391, 1024, 0, stream>>>(S16, gcursor, staging, bias, out);
}

// Round 8
// 148.122 us; speedup vs baseline: 5.3474x; 5.3474x over previous
//
#include <hip/hip_runtime.h>

// GCN layer: out = A_sparse @ (X @ W) + bias
// R8: revert R7's f32-LDS-atomic gather (f32 atomic lane throughput measured
// ~0.25/cy/CU -> 102M lane-ops is structurally unaffordable). Keep the fused
// gemm||pass1 kernel (R7's win). New: per-bucket sort fused INTO the gather
// kernel via an LDS perm array (int LDS atomics only); register accumulate +
// shfl_xor reduce as in R6. Staging is read from global exactly once.

#define N_NODES 50000
#define N_EDGES 800000
#define D 128
#define NBUCKET 392            // bucket = row >> 7 (128 rows each)
#define SLOT 2560              // per-bucket capacity (mean 2041, +11.5 sigma)
#define CHUNK 2048             // edges per pass1 block
#define EPT 8                  // CHUNK/256
#define GEMM_BLOCKS 782        // ceil(50000/64)
#define PASS1_BLOCKS 391       // ceil(800000/2048)

typedef short bf16x8 __attribute__((ext_vector_type(8)));
typedef float f32x4 __attribute__((ext_vector_type(4)));

__device__ inline unsigned short f2bf(float f) {   // RNE f32 -> bf16 bits
    unsigned u = __float_as_uint(f);
    unsigned r = (u + 0x7FFFu + ((u >> 16) & 1u)) >> 16;
    return (unsigned short)r;
}

// ---- ws layout (bytes) ----
// S16:      [0, 12800000)            50000*128*2 bf16
// staging:  [12800000, 20828160)     392*2560 int2 (row<<16|col, bits(w))
// gcursor:  [20828160, +1568)        392 bucket cursors

// ---------------- K0: zero bucket cursors ----------------
__global__ void zero_kernel(int* __restrict__ gcursor) {
    int t = threadIdx.x;
    if (t < NBUCKET) gcursor[t] = 0;
}

// ---------------- K1: fused gemm (blocks < GEMM_BLOCKS) + pass1 ------------
__global__ __launch_bounds__(256) void fused_kernel(const float* __restrict__ X,
                                                    const float* __restrict__ W,
                                                    unsigned short* __restrict__ S16,
                                                    const int* __restrict__ ei,
                                                    const float* __restrict__ ew,
                                                    int* __restrict__ gcursor,
                                                    int2* __restrict__ staging) {
    __shared__ __align__(16) char shmem[52224];
    const int t = threadIdx.x;
    const int lane = t & 63, wid = t >> 6;

    if (blockIdx.x < GEMM_BLOCKS) {
        // ================= GEMM: S16 = bf16(X @ W) =================
        unsigned short* wt = (unsigned short*)shmem;            // [128][136]
        unsigned short* xt = (unsigned short*)(shmem + 34816);  // [64][136]
        const int row0 = blockIdx.x * 64;

#pragma unroll
        for (int i = 0; i < 64; ++i) {
            int idx = t + 256 * i;            // flat over [k][n]
            float w = W[idx];
            int k = idx >> 7, n = idx & 127;
            wt[n * 136 + k] = f2bf(w);
        }
        const float4* X4 = (const float4*)X;
#pragma unroll
        for (int i = 0; i < 8; ++i) {
            int idx4 = t + 256 * i;
            int r = idx4 >> 5, c4 = idx4 & 31;
            int gr = row0 + r;
            float4 v = make_float4(0.f, 0.f, 0.f, 0.f);
            if (gr < N_NODES) v = X4[gr * 32 + c4];
            ushort4 u = make_ushort4(f2bf(v.x), f2bf(v.y), f2bf(v.z), f2bf(v.w));
            *(ushort4*)&xt[r * 136 + c4 * 4] = u;
        }
        __syncthreads();

        const int m = lane & 15;
        const int q = lane >> 4;
        const int rbase = wid * 16;

        f32x4 acc[8];
#pragma unroll
        for (int nt = 0; nt < 8; ++nt) acc[nt] = (f32x4){0.f, 0.f, 0.f, 0.f};
#pragma unroll
        for (int ks = 0; ks < 4; ++ks) {
            bf16x8 a = *(const bf16x8*)&xt[(rbase + m) * 136 + ks * 32 + q * 8];
#pragma unroll
            for (int nt = 0; nt < 8; ++nt) {
                bf16x8 b = *(const bf16x8*)&wt[(nt * 16 + m) * 136 + ks * 32 + q * 8];
                acc[nt] = __builtin_amdgcn_mfma_f32_16x16x32_bf16(a, b, acc[nt], 0, 0, 0);
            }
        }
        __syncthreads();
#pragma unroll
        for (int nt = 0; nt < 8; ++nt) {
            int col = nt * 16 + m;
#pragma unroll
            for (int r = 0; r < 4; ++r) {
                int rl = rbase + q * 4 + r;
                xt[rl * 136 + col] = f2bf(acc[nt][r]);
            }
        }
        __syncthreads();
#pragma unroll
        for (int i = 0; i < 4; ++i) {
            int id = t + 256 * i;
            int r = id >> 4, c8 = (id & 15) * 8;
            int gr = row0 + r;
            if (gr < N_NODES)
                *(uint4*)&S16[gr * 128 + c8] = *(const uint4*)&xt[r * 136 + c8];
        }
    } else {
        // ================= PASS1: bucket multisplit (392 buckets) =========
        int2* buf            = (int2*)shmem;                        // [2048]
        unsigned short* bof  = (unsigned short*)(shmem + 16384);    // [2048]
        int* hist            = (int*)(shmem + 20480);               // [512]
        int* lcur            = (int*)(shmem + 22528);               // [512]
        int* bmg             = (int*)(shmem + 24576);               // [512]
        int* wsum            = (int*)(shmem + 26624);               // [4]
        const int base = (blockIdx.x - GEMM_BLOCKS) * CHUNK;

        hist[t] = 0;
        hist[t + 256] = 0;
        __syncthreads();

        int rows[EPT];
#pragma unroll
        for (int i = 0; i < EPT; ++i) {
            int e = base + t + 256 * i;
            rows[i] = (e < N_EDGES) ? ei[e] : -1;
            if (rows[i] >= 0) atomicAdd(&hist[rows[i] >> 7], 1);
        }
        __syncthreads();

        // two-phase wave-shfl exclusive scan of hist[512]
        int run = 0, exv[2], vv[2];
#pragma unroll
        for (int ph = 0; ph < 2; ++ph) {
            int v = hist[ph * 256 + t];
            vv[ph] = v;
            int incl = v;
#pragma unroll
            for (int off = 1; off < 64; off <<= 1) {
                int x = __shfl_up(incl, off, 64);
                if (lane >= off) incl += x;
            }
            if (lane == 63) wsum[wid] = incl;
            __syncthreads();
            int pre = 0, tot = 0;
#pragma unroll
            for (int w = 0; w < 4; ++w) {
                int x = wsum[w];
                if (w < wid) pre += x;
                tot += x;
            }
            exv[ph] = run + incl - v + pre;
            run += tot;
            __syncthreads();
        }
        const int total = run;
        lcur[t] = exv[0];
        lcur[t + 256] = exv[1];
#pragma unroll
        for (int ph = 0; ph < 2; ++ph) {
            int b = ph * 256 + t;
            if (b < NBUCKET) {
                int v = vv[ph];
                int gb = 0;
                if (v > 0) gb = atomicAdd(&gcursor[b], v);
                bmg[b] = b * SLOT + gb - exv[ph];
            }
        }
        __syncthreads();

        // local reorder into bucket-contiguous LDS
#pragma unroll
        for (int i = 0; i < EPT; ++i) {
            if (rows[i] >= 0) {
                int e = base + t + 256 * i;
                int col = ei[N_EDGES + e];
                float w = ew[e];
                int b = rows[i] >> 7;
                int lp = atomicAdd(&lcur[b], 1);
                buf[lp] = make_int2((int)(((unsigned)rows[i] << 16) | (unsigned)col),
                                    __float_as_int(w));
                bof[lp] = (unsigned short)b;
            }
        }
        __syncthreads();

        // coalesced sweep: consecutive lp in same bucket -> consecutive gaddr
        for (int lp = t; lp < total; lp += 256) {
            int b = bof[lp];
            int g = bmg[b] + lp;
            if (g < (b + 1) * SLOT) staging[g] = buf[lp];   // overflow guard
        }
    }
}

// ---------------- K2: fused per-bucket sort + gather ----------------
// One 1024-thread block per 128-row bucket. Phase A: load bucket to LDS,
// int-atomic hist by local row, wave-shfl scan, build perm[] (sort via
// indices -- no data movement, no global write-back). Phase B: per-row
// register gather (8 edges in flight per wave: sub=lane>>3, q=lane&7 owns
// 16 dims via 2x uint4), shfl_xor reduce, coalesced +bias store.
__global__ __launch_bounds__(1024) void sortgather_kernel(const unsigned short* __restrict__ S16,
                                                          const int* __restrict__ gcursor,
                                                          const int2* __restrict__ staging,
                                                          const float* __restrict__ bias,
                                                          float* __restrict__ out) {
    __shared__ int2 in0[SLOT];              // 20480 B
    __shared__ unsigned short perm[SLOT];   // 5120 B
    __shared__ int hist[128];
    __shared__ int exs[128];
    __shared__ int lcur[128];
    __shared__ int wsum[2];
    const int t = threadIdx.x;
    const int b = blockIdx.x;
    const int lane = t & 63;
    int cnt = gcursor[b];
    if (cnt > SLOT) cnt = SLOT;

    if (t < 128) hist[t] = 0;
    __syncthreads();

    for (int i = t; i < cnt; i += 1024) {
        int2 v = staging[b * SLOT + i];
        in0[i] = v;
        atomicAdd(&hist[((unsigned)v.x >> 16) & 127u], 1);
    }
    __syncthreads();

    // scan hist[128] using threads 0..127 (2 full waves)
    int v = 0, incl = 0;
    if (t < 128) {
        v = hist[t];
        incl = v;
#pragma unroll
        for (int off = 1; off < 64; off <<= 1) {
            int x = __shfl_up(incl, off, 64);
            if (lane >= off) incl += x;
        }
        if (lane == 63) wsum[t >> 6] = incl;
    }
    __syncthreads();
    if (t < 128) {
        int pre = (t >= 64) ? wsum[0] : 0;
        int ex = incl - v + pre;
        exs[t] = ex;
        lcur[t] = ex;
    }
    __syncthreads();

    // build perm: sorted position -> original index
    for (int i = t; i < cnt; i += 1024) {
        int lr = (int)(((unsigned)in0[i].x >> 16) & 127u);
        int p = atomicAdd(&lcur[lr], 1);
        perm[p] = (unsigned short)i;
    }
    __syncthreads();

    // gather: wave wv handles rows wv, wv+16, ... (8 rows each)
    const int wv = t >> 6;
    const int sub = lane >> 3;
    const int q = lane & 7;
    const uint4* S4 = (const uint4*)S16;     // row stride: 16 uint4
    const float4* bias4 = (const float4*)bias;
    float4 bb[4];
#pragma unroll
    for (int j = 0; j < 4; ++j) bb[j] = bias4[q * 4 + j];

    for (int rr = wv; rr < 128; rr += 16) {
        int beg = exs[rr];
        int end = beg + hist[rr];
        float acc[16];
#pragma unroll
        for (int i = 0; i < 16; ++i) acc[i] = 0.f;
        for (int p = beg + sub; p < end; p += 8) {
            int idx = perm[p];
            int2 cw = in0[idx];
            float w = __int_as_float(cw.y);
            int col = cw.x & 0xFFFF;
            uint4 v0 = S4[col * 16 + q * 2];
            uint4 v1 = S4[col * 16 + q * 2 + 1];
            acc[0]  += __uint_as_float(v0.x << 16) * w;
            acc[1]  += __uint_as_float(v0.x & 0xFFFF0000u) * w;
            acc[2]  += __uint_as_float(v0.y << 16) * w;
            acc[3]  += __uint_as_float(v0.y & 0xFFFF0000u) * w;
            acc[4]  += __uint_as_float(v0.z << 16) * w;
            acc[5]  += __uint_as_float(v0.z & 0xFFFF0000u) * w;
            acc[6]  += __uint_as_float(v0.w << 16) * w;
            acc[7]  += __uint_as_float(v0.w & 0xFFFF0000u) * w;
            acc[8]  += __uint_as_float(v1.x << 16) * w;
            acc[9]  += __uint_as_float(v1.x & 0xFFFF0000u) * w;
            acc[10] += __uint_as_float(v1.y << 16) * w;
            acc[11] += __uint_as_float(v1.y & 0xFFFF0000u) * w;
            acc[12] += __uint_as_float(v1.z << 16) * w;
            acc[13] += __uint_as_float(v1.z & 0xFFFF0000u) * w;
            acc[14] += __uint_as_float(v1.w << 16) * w;
            acc[15] += __uint_as_float(v1.w & 0xFFFF0000u) * w;
        }
#pragma unroll
        for (int i = 0; i < 16; ++i) acc[i] += __shfl_xor(acc[i], 8, 64);
#pragma unroll
        for (int i = 0; i < 16; ++i) acc[i] += __shfl_xor(acc[i], 16, 64);
#pragma unroll
        for (int i = 0; i < 16; ++i) acc[i] += __shfl_xor(acc[i], 32, 64);
        int gr = b * 128 + rr;
        if (sub == 0 && gr < N_NODES) {
#pragma unroll
            for (int j = 0; j < 4; ++j) {
                float4 o = make_float4(acc[4 * j + 0] + bb[j].x, acc[4 * j + 1] + bb[j].y,
                                       acc[4 * j + 2] + bb[j].z, acc[4 * j + 3] + bb[j].w);
                ((float4*)out)[gr * 32 + q * 4 + j] = o;
            }
        }
    }
}

extern "C" void kernel_launch(void* const* d_in, const int* in_sizes, int n_in,
                              void* d_out, int out_size, void* d_ws, size_t ws_size,
                              hipStream_t stream) {
    const float* X    = (const float*)d_in[0];
    const int*   ei   = (const int*)d_in[1];
    const float* ew   = (const float*)d_in[2];
    const float* W    = (const float*)d_in[3];
    const float* bias = (const float*)d_in[4];
    float* out = (float*)d_out;

    char* ws = (char*)d_ws;
    unsigned short* S16 = (unsigned short*)(ws);
    int2* staging = (int2*)(ws + 12800000);
    int*  gcursor = (int*)(ws + 20828160);

    zero_kernel<<<1, 512, 0, stream>>>(gcursor);
    fused_kernel<<<GEMM_BLOCKS + PASS1_BLOCKS, 256, 0, stream>>>(X, W, S16, ei, ew,
                                                                 gcursor, staging);
    sortgather_kernel<<<NBUCKET, 1024, 0, stream>>>(S16, gcursor, staging, bias, out);
}